// Round 10
// baseline (413.200 us; speedup 1.0000x reference)
//
#include <hip/hip_runtime.h>
#include <hip/hip_bf16.h>
#include <math.h>

#define BB 16
#define NN 512
#define DD 256
#define KK 12

typedef __bf16 bf16x8 __attribute__((ext_vector_type(8)));
typedef __bf16 bf16x4 __attribute__((ext_vector_type(4)));
typedef float  f32x4  __attribute__((ext_vector_type(4)));

// workspace layout (bytes)
#define WS_WM     0              // wm[b,n] f32, 32KB
#define WS_NCNT   32768          // ncnt[b,m] int32 (atomic), 32KB
#define WS_NODEBF 65536          // node bf16 [B][N][D], 4MB
#define WS_NODET  4259840        // node_t bf16 [B][D][N] scaled by wm, 4MB
#define WS_WKBF   8454144        // Wk bf16 [K][D][D], 1.5MB
#define WS_WSBF   10027008       // Ws bf16 [D][D], 128KB
#define WS_T      10158080       // T bf16 [B][N][K][E] = [b,m,k,e], 50MB

// ---------------------------------------------------------------- k1: w, all_weight, wm, node_bf16
__global__ __launch_bounds__(256) void k1_prep(const float* __restrict__ node,
        const float* __restrict__ Ww, const float* __restrict__ bw,
        const int* __restrict__ node_mask,
        float* __restrict__ wm, __bf16* __restrict__ node_bf, float* __restrict__ all_w) {
    int t = threadIdx.x;
    int lane = t & 63;
    int row = blockIdx.x * 4 + (t >> 6);           // b*N + n
    const float4 nv = *(const float4*)(node + (size_t)row * DD + lane * 4);
    const float4 wv = *(const float4*)(Ww + lane * 4);
    float dot = nv.x*wv.x + nv.y*wv.y + nv.z*wv.z + nv.w*wv.w;
    #pragma unroll
    for (int off = 32; off > 0; off >>= 1) dot += __shfl_xor(dot, off);
    float w = 1.0f / (1.0f + expf(-(dot + bw[0])));
    int mk = node_mask[row];
    if (lane == 0) {
        wm[row]    = w * (float)mk;
        all_w[row] = w;
    }
    bf16x4 nb = {(__bf16)nv.x, (__bf16)nv.y, (__bf16)nv.z, (__bf16)nv.w};
    *(bf16x4*)(node_bf + (size_t)row * DD + lane * 4) = nb;
}

// ---------------------------------------------------------------- k1b: Wk, Ws -> bf16
__global__ __launch_bounds__(256) void k1b_convert(const float* __restrict__ Wk,
        const float* __restrict__ Ws, __bf16* __restrict__ Wk_bf, __bf16* __restrict__ Ws_bf) {
    const int KDD = KK * DD * DD;
    int idx = (blockIdx.x * 256 + threadIdx.x) * 4;
    if (idx < KDD) {
        float4 v = *(const float4*)(Wk + idx);
        bf16x4 o = {(__bf16)v.x, (__bf16)v.y, (__bf16)v.z, (__bf16)v.w};
        *(bf16x4*)(Wk_bf + idx) = o;
    } else {
        int j = idx - KDD;
        if (j < DD * DD) {
            float4 v = *(const float4*)(Ws + j);
            bf16x4 o = {(__bf16)v.x, (__bf16)v.y, (__bf16)v.z, (__bf16)v.w};
            *(bf16x4*)(Ws_bf + j) = o;
        }
    }
}

// ---------------------------------------------------------------- k2: node fp32 [B][N][D] -> node_t bf16 [B][D][N] scaled by wm[b,n]
__global__ __launch_bounds__(256) void k2_transpose(const float* __restrict__ node,
        const float* __restrict__ wm, __bf16* __restrict__ dst) {
    __shared__ float tile[64][65];
    int bx = blockIdx.x;
    int b = bx >> 5; int rest = bx & 31; int nt = rest >> 2; int dt = rest & 3;
    int n0 = nt * 64, d0 = dt * 64;
    int t = threadIdx.x;
    #pragma unroll
    for (int i = 0; i < 16; i++) {
        int idx = i * 256 + t;
        int n = idx >> 6, d = idx & 63;
        tile[n][d] = node[((size_t)(b * NN + n0 + n)) * DD + d0 + d];
    }
    __syncthreads();
    #pragma unroll
    for (int i = 0; i < 16; i++) {
        int idx = i * 256 + t;
        int d = idx >> 6, n = idx & 63;
        float w = wm[b * NN + n0 + n];
        dst[((size_t)(b * DD + d0 + d)) * NN + n0 + n] = (__bf16)(tile[n][d] * w);
    }
}

// ---------------------------------------------------------------- kA: stage A. T[b,m,k,e] = sum_n g[m,n](n!=m) * wnode[n,e]
// 64-row m-tile, 4 n-rounds of 128, MLP-16 staging (8 g + 8 mask int4 in flight),
// next-round prefetch overlaps MFMA. Counts via packed-u16 VALU + one atomic per row.
__global__ __launch_bounds__(256) void kA_stageA(const int* __restrict__ graphs,
        const int* __restrict__ node_mask, const __bf16* __restrict__ node_t,
        __bf16* __restrict__ T, int* __restrict__ ncnt) {
    __shared__ __align__(16) __bf16 Asub[64][136];  // 17.4 KB
    int bx = blockIdx.x;
    int b  = (bx & 7) + 8 * ((bx >> 3) & 1);        // b%8 = XCD id
    int mt = (bx >> 4) & 7;
    int k  = bx >> 7;                                // 0..11
    int m0 = mt * 64;
    int t = threadIdx.x;
    int lane = t & 63;
    int w = t >> 6;                                  // wave 0..3
    int q = lane >> 4;
    int l16 = lane & 15;
    int esub = w * 64;                               // wave's 64-wide e-slice

    f32x4 acc[4][4];
    #pragma unroll
    for (int i = 0; i < 4; i++)
        #pragma unroll
        for (int j = 0; j < 4; j++) acc[i][j] = (f32x4){0.f, 0.f, 0.f, 0.f};

    int arow = t >> 2;                               // 0..63
    int aq   = t & 3;                                // 32-col subchunk
    const int* grow = graphs + ((size_t)((k * BB + b) * NN + m0 + arow)) * NN;
    const int* mrow = node_mask + b * NN;
    int mg = m0 + arow;
    unsigned cnt = 0;

    // prefetch round 0
    int4 g[8], mk[8];
    {
        int nbase0 = aq * 32;
        #pragma unroll
        for (int i = 0; i < 8; i++) g[i]  = *(const int4*)(grow + nbase0 + i * 4);
        #pragma unroll
        for (int i = 0; i < 8; i++) mk[i] = *(const int4*)(mrow + nbase0 + i * 4);
    }

    #pragma unroll 1
    for (int r0 = 0; r0 < 4; r0++) {
        // ---- convert prefetched regs -> bf16 LDS, diag cleared, counts fused
        int nbase0 = r0 * 128 + aq * 32;
        #pragma unroll
        for (int i = 0; i < 8; i++) {
            int nb = nbase0 + i * 4;
            unsigned p0 = (unsigned)g[i].x | ((unsigned)g[i].y << 16);
            unsigned p1 = (unsigned)g[i].z | ((unsigned)g[i].w << 16);
            unsigned drel = (unsigned)(mg - nb);
            if (drel < 2u)      p0 &= ~(0xFFFFu << (16 * drel));
            else if (drel < 4u) p1 &= ~(0xFFFFu << (16 * (drel - 2)));
            unsigned mp0 = (unsigned)mk[i].x | ((unsigned)mk[i].y << 16);
            unsigned mp1 = (unsigned)mk[i].z | ((unsigned)mk[i].w << 16);
            cnt += (p0 & mp0) + (p1 & mp1);
            uint2 st; st.x = p0 * 0x3F80u; st.y = p1 * 0x3F80u;
            *(uint2*)&Asub[arow][aq * 32 + i * 4] = st;
        }
        __syncthreads();                             // Asub ready

        // ---- prefetch next round (latency overlaps MFMA below)
        if (r0 < 3) {
            int nb1 = (r0 + 1) * 128 + aq * 32;
            #pragma unroll
            for (int i = 0; i < 8; i++) g[i]  = *(const int4*)(grow + nb1 + i * 4);
            #pragma unroll
            for (int i = 0; i < 8; i++) mk[i] = *(const int4*)(mrow + nb1 + i * 4);
        }

        // ---- MFMA over 4 chunks of 32
        #pragma unroll
        for (int kk = 0; kk < 4; kk++) {
            int n0c = r0 * 128 + kk * 32;
            int lc  = kk * 32;
            bf16x8 af[4], bfr[4];
            #pragma unroll
            for (int fm = 0; fm < 4; fm++)
                af[fm] = *(const bf16x8*)&Asub[fm * 16 + l16][lc + q * 8];
            #pragma unroll
            for (int fd = 0; fd < 4; fd++)
                bfr[fd] = *(const bf16x8*)(node_t +
                    ((size_t)(b * DD + esub + fd * 16 + l16)) * NN + n0c + q * 8);
            #pragma unroll
            for (int fm = 0; fm < 4; fm++)
                #pragma unroll
                for (int fd = 0; fd < 4; fd++)
                    acc[fm][fd] = __builtin_amdgcn_mfma_f32_16x16x32_bf16(
                        af[fm], bfr[fd], acc[fm][fd], 0, 0, 0);
        }
        __syncthreads();                             // Asub free for next convert
    }

    // ---- counts: fold u16 halves, reduce over the 4 aq lanes, one atomic per row
    cnt = (cnt & 0xFFFFu) + (cnt >> 16);
    int ci = (int)cnt;
    ci += __shfl_xor(ci, 1);
    ci += __shfl_xor(ci, 2);
    if (aq == 0) atomicAdd(&ncnt[b * NN + mg], ci);

    // ---- store T bf16 [b,m,k,e] (rows contiguous for kB). C/D: col=l16, row=q*4+r
    #pragma unroll
    for (int fm = 0; fm < 4; fm++)
        #pragma unroll
        for (int fd = 0; fd < 4; fd++) {
            int col = esub + fd * 16 + l16;
            #pragma unroll
            for (int r = 0; r < 4; r++) {
                int m = m0 + fm * 16 + q * 4 + r;
                T[((size_t)((b * NN + m) * KK + k)) * DD + col] = (__bf16)acc[fm][fd][r];
            }
        }
}

// ---------------------------------------------------------------- kB: stage B + self + epilogue
// out[b,m,d] = relu( s*Σ_k T[b,m,k,:]·Wk[k,d,:] + node·Ws[d,:] + bs[d] )
// 32-row x 128-col tiles, grid 512 (2+/CU). T rows staged coalesced; W frags from L2.
__global__ __launch_bounds__(256) void kB_stageB(const __bf16* __restrict__ T,
        const __bf16* __restrict__ Wk_bf, const __bf16* __restrict__ node_bf,
        const __bf16* __restrict__ Ws_bf, const float* __restrict__ bs,
        const int* __restrict__ ncnt, const int* __restrict__ node_mask,
        float* __restrict__ out) {
    __shared__ __align__(16) __bf16 At[32][264];    // 16.9 KB
    __shared__ float sm[32];
    int bx = blockIdx.x;
    int b  = (bx & 7) + 8 * ((bx >> 3) & 1);
    int mt = (bx >> 4) & 15;
    int dh = bx >> 8;                                // 0/1
    int m0 = mt * 32;
    int t = threadIdx.x;
    int lane = t & 63;
    int w = t >> 6;
    int q = lane >> 4;
    int l16 = lane & 15;
    int dsub = dh * 128 + w * 32;

    if (t < 32) {
        int c  = ncnt[b * NN + m0 + t];
        int mk = node_mask[b * NN + m0 + t];
        sm[t] = (float)mk / (float)(c >= 1 ? c : 1);
    }

    f32x4 acc[2][2];
    #pragma unroll
    for (int i = 0; i < 2; i++)
        #pragma unroll
        for (int j = 0; j < 2; j++) acc[i][j] = (f32x4){0.f, 0.f, 0.f, 0.f};

    int srow  = t >> 3;                              // 0..31
    int scol8 = (t & 7) * 8;                         // 0..56

    #pragma unroll 1
    for (int k = 0; k < KK; k++) {
        // ---- stage T rows (512B contiguous per row, 4 bf16x8/thread)
        const __bf16* trow = T + ((size_t)((b * NN + m0 + srow) * KK + k)) * DD;
        bf16x8 a0 = *(const bf16x8*)(trow + scol8);
        bf16x8 a1 = *(const bf16x8*)(trow + scol8 + 64);
        bf16x8 a2 = *(const bf16x8*)(trow + scol8 + 128);
        bf16x8 a3 = *(const bf16x8*)(trow + scol8 + 192);
        *(bf16x8*)&At[srow][scol8]       = a0;
        *(bf16x8*)&At[srow][scol8 + 64]  = a1;
        *(bf16x8*)&At[srow][scol8 + 128] = a2;
        *(bf16x8*)&At[srow][scol8 + 192] = a3;
        __syncthreads();
        // ---- MFMA: 8 e-chunks of 32
        #pragma unroll
        for (int ee = 0; ee < 8; ee++) {
            int e0c = ee * 32;
            bf16x8 afT[2], bw2[2];
            #pragma unroll
            for (int fm = 0; fm < 2; fm++)
                afT[fm] = *(const bf16x8*)&At[fm * 16 + l16][e0c + q * 8];
            #pragma unroll
            for (int fd = 0; fd < 2; fd++)
                bw2[fd] = *(const bf16x8*)(Wk_bf +
                    ((size_t)(k * DD + dsub + fd * 16 + l16)) * DD + e0c + q * 8);
            #pragma unroll
            for (int fm = 0; fm < 2; fm++)
                #pragma unroll
                for (int fd = 0; fd < 2; fd++)
                    acc[fm][fd] = __builtin_amdgcn_mfma_f32_16x16x32_bf16(
                        afT[fm], bw2[fd], acc[fm][fd], 0, 0, 0);
        }
        __syncthreads();
    }

    // scale aggregate by s[b,m]
    #pragma unroll
    for (int fm = 0; fm < 2; fm++)
        #pragma unroll
        for (int r = 0; r < 4; r++) {
            float s = sm[fm * 16 + q * 4 + r];
            acc[fm][0][r] *= s;
            acc[fm][1][r] *= s;
        }

    // ---- self round: stage node_bf rows, MFMA with Ws
    {
        const __bf16* nrow = node_bf + (size_t)(b * NN + m0 + srow) * DD;
        bf16x8 a0 = *(const bf16x8*)(nrow + scol8);
        bf16x8 a1 = *(const bf16x8*)(nrow + scol8 + 64);
        bf16x8 a2 = *(const bf16x8*)(nrow + scol8 + 128);
        bf16x8 a3 = *(const bf16x8*)(nrow + scol8 + 192);
        *(bf16x8*)&At[srow][scol8]       = a0;
        *(bf16x8*)&At[srow][scol8 + 64]  = a1;
        *(bf16x8*)&At[srow][scol8 + 128] = a2;
        *(bf16x8*)&At[srow][scol8 + 192] = a3;
        __syncthreads();
        #pragma unroll
        for (int ee = 0; ee < 8; ee++) {
            int e0c = ee * 32;
            bf16x8 afS[2], bwS[2];
            #pragma unroll
            for (int fm = 0; fm < 2; fm++)
                afS[fm] = *(const bf16x8*)&At[fm * 16 + l16][e0c + q * 8];
            #pragma unroll
            for (int fd = 0; fd < 2; fd++)
                bwS[fd] = *(const bf16x8*)(Ws_bf +
                    ((size_t)(dsub + fd * 16 + l16)) * DD + e0c + q * 8);
            #pragma unroll
            for (int fm = 0; fm < 2; fm++)
                #pragma unroll
                for (int fd = 0; fd < 2; fd++)
                    acc[fm][fd] = __builtin_amdgcn_mfma_f32_16x16x32_bf16(
                        afS[fm], bwS[fd], acc[fm][fd], 0, 0, 0);
        }
    }

    // ---- epilogue: + bs, relu, store f32
    #pragma unroll
    for (int fm = 0; fm < 2; fm++)
        #pragma unroll
        for (int fd = 0; fd < 2; fd++) {
            int d = dsub + fd * 16 + l16;
            float bsv = bs[d];
            #pragma unroll
            for (int r = 0; r < 4; r++) {
                int m = m0 + fm * 16 + q * 4 + r;
                float v = acc[fm][fd][r] + bsv;
                out[((size_t)(b * NN + m)) * DD + d] = fmaxf(v, 0.0f);
            }
        }
}

// ----------------------------------------------------------------
extern "C" void kernel_launch(void* const* d_in, const int* in_sizes, int n_in,
                              void* d_out, int out_size, void* d_ws, size_t ws_size,
                              hipStream_t stream) {
    const float* node      = (const float*)d_in[0];
    const float* Ww        = (const float*)d_in[1];
    const float* bw        = (const float*)d_in[2];
    const float* Ws        = (const float*)d_in[3];
    const float* bs        = (const float*)d_in[4];
    const float* Wk        = (const float*)d_in[5];
    const int*   node_mask = (const int*)d_in[6];
    const int*   graphs    = (const int*)d_in[7];
    float* out   = (float*)d_out;
    float* all_w = out + (size_t)BB * NN * DD;

    char* ws = (char*)d_ws;
    float*  wm      = (float*)(ws + WS_WM);
    int*    ncnt    = (int*)(ws + WS_NCNT);
    __bf16* node_bf = (__bf16*)(ws + WS_NODEBF);
    __bf16* node_t  = (__bf16*)(ws + WS_NODET);
    __bf16* Wk_bf   = (__bf16*)(ws + WS_WKBF);
    __bf16* Ws_bf   = (__bf16*)(ws + WS_WSBF);
    __bf16* Tbuf    = (__bf16*)(ws + WS_T);

    hipMemsetAsync(ncnt, 0, BB * NN * sizeof(int), stream);
    k1_prep    <<<2048, 256, 0, stream>>>(node, Ww, bw, node_mask, wm, node_bf, all_w);
    k1b_convert<<< 832, 256, 0, stream>>>(Wk, Ws, Wk_bf, Ws_bf);
    k2_transpose<<<512, 256, 0, stream>>>(node, wm, node_t);
    kA_stageA  <<<1536, 256, 0, stream>>>(graphs, node_mask, node_t, Tbuf, ncnt);
    kB_stageB  <<< 512, 256, 0, stream>>>(Tbuf, Wk_bf, node_bf, Ws_bf, bs, ncnt, node_mask, out);
}